// Round 1
// baseline (10046.066 us; speedup 1.0000x reference)
//
#include <hip/hip_runtime.h>
#include <cmath>

#define HH 64
#define WD 64
#define CIN 256
#define COUT 256
#define NB 32

#define COB 8   // output channels per block
#define CK 4    // input channels per LDS chunk

// ---------------------------------------------------------------------------
// Kernel 1: direct 3x3 conv, fp32, NCHW. Block: 256 threads.
// Tile: 8 co x 32 rows x 64 cols. Thread: 1 col (lane), 8 rows, 8 co.
// ---------------------------------------------------------------------------
__global__ __launch_bounds__(256) void conv3x3_kernel(const float* __restrict__ x,
                                                      const float* __restrict__ w,
                                                      float* __restrict__ y) {
    __shared__ float xs[CK][34][66];
    __shared__ float wsh[COB][CK][9];
    const int tid = threadIdx.x;
    const int co0 = blockIdx.x * COB;   // 32 co-blocks (fastest -> L2 reuse of x)
    const int h0  = blockIdx.y * 32;    // 2 row-tiles
    const int n   = blockIdx.z;         // 32 images
    const int c0  = tid & 63;           // output col  (lane)
    const int r0  = (tid >> 6) * 8;     // output row base (wave-uniform)

    float acc[COB][8];
    #pragma unroll
    for (int a = 0; a < COB; ++a)
        #pragma unroll
        for (int b = 0; b < 8; ++b) acc[a][b] = 0.f;

    const float* xn = x + (size_t)n * CIN * HH * WD;

    for (int ci0 = 0; ci0 < CIN; ci0 += CK) {
        __syncthreads();
        // stage x: CK x 34 x 66 (rows h0-1..h0+32, cols -1..64, zero-padded)
        for (int idx = tid; idx < CK * 34 * 66; idx += 256) {
            int ci  = idx / (34 * 66);
            int rem = idx - ci * (34 * 66);
            int rr  = rem / 66;
            int cc  = rem - rr * 66;
            int gh  = h0 - 1 + rr;
            int gw  = cc - 1;
            float v = 0.f;
            if (gh >= 0 && gh < HH && gw >= 0 && gw < WD)
                v = xn[(size_t)(ci0 + ci) * (HH * WD) + gh * WD + gw];
            xs[ci][rr][cc] = v;
        }
        // stage w: COB x CK x 9
        for (int idx = tid; idx < COB * CK * 9; idx += 256) {
            int co  = idx / (CK * 9);
            int rem = idx - co * (CK * 9);
            int ci  = rem / 9;
            int k   = rem - ci * 9;
            wsh[co][ci][k] = w[(size_t)(co0 + co) * (CIN * 9) + (ci0 + ci) * 9 + k];
        }
        __syncthreads();

        #pragma unroll
        for (int ci = 0; ci < CK; ++ci) {
            float xv[10][3];
            #pragma unroll
            for (int rr = 0; rr < 10; ++rr)
                #pragma unroll
                for (int cc = 0; cc < 3; ++cc)
                    xv[rr][cc] = xs[ci][r0 + rr][c0 + cc];
            #pragma unroll
            for (int ky = 0; ky < 3; ++ky)
                #pragma unroll
                for (int kx = 0; kx < 3; ++kx)
                    #pragma unroll
                    for (int co = 0; co < COB; ++co) {
                        const float wv = wsh[co][ci][ky * 3 + kx];
                        #pragma unroll
                        for (int i = 0; i < 8; ++i)
                            acc[co][i] = fmaf(wv, xv[i + ky][kx], acc[co][i]);
                    }
        }
    }

    #pragma unroll
    for (int co = 0; co < COB; ++co) {
        float* yp = y + ((size_t)n * COUT + co0 + co) * (HH * WD);
        #pragma unroll
        for (int i = 0; i < 8; ++i)
            yp[(h0 + r0 + i) * WD + c0] = acc[co][i];
    }
}

// ---------------------------------------------------------------------------
// Kernel 2: per-(n,c)-plane separable circulant deconvolution, in-place on y.
// y_out = C_u * Y * C_v^T ; generators g_u,g_v computed per block from alpha.
// ---------------------------------------------------------------------------
__global__ __launch_bounds__(256) void arma_solve_kernel(const float* __restrict__ alpha,
                                                         float* __restrict__ y) {
    __shared__ float Ys[64][66];
    __shared__ float Ts[64][66];
    __shared__ float gsh[128];   // [0..63]=g_u (rows/H), [64..127]=g_v (cols/W)
    const int tid = threadIdx.x;
    const int plane = blockIdx.x;       // n*256 + c
    const int c = plane & 255;
    float* yp = y + (size_t)plane * (64 * 64);

    // load plane (coalesced float4)
    #pragma unroll
    for (int k = 0; k < 4; ++k) {
        const int off = k * 1024 + tid * 4;
        const int rr = off >> 6;
        const int cc = off & 63;
        const float4 v = *reinterpret_cast<const float4*>(yp + off);
        Ys[rr][cc] = v.x; Ys[rr][cc + 1] = v.y; Ys[rr][cc + 2] = v.z; Ys[rr][cc + 3] = v.w;
    }

    // g computation: tid<64 -> g_u (from alpha row a=0), tid in [64,128) -> g_v (a=1)
    if (tid < 128) {
        const int r   = tid & 63;
        const int isv = tid >> 6;
        const float t0 = tanhf(alpha[c * 4 + isv * 2 + 0]);
        const float t1 = tanhf(alpha[c * 4 + isv * 2 + 1]);
        const float q = 0.70710678118654752f;
        const float a0 = q * (t0 + t1);   // tap at offset -1 (index 0 of the 3-vec)
        const float a2 = q * (t1 - t0);   // tap at offset +1 (index 2 of the 3-vec)
        const float w0 = 0.09817477042468103f; // 2*pi/64
        float s = 0.f;
        for (int p = 0; p < 64; ++p) {
            const float th = w0 * (float)p;
            const float re = 1.f + (a0 + a2) * cosf(th);
            const float im = (a0 - a2) * sinf(th);
            const float inv = 1.f / (re * re + im * im);
            const int pr = (p * r) & 63;
            const float ph = w0 * (float)pr;
            s += (cosf(ph) * re + sinf(ph) * im) * inv;
        }
        gsh[tid] = s * (1.0f / 64.0f);
    }
    __syncthreads();

    const int r0 = (tid >> 4) * 4;
    const int s0 = (tid & 15) * 4;

    // pass A (along W): Ts[r][s] = sum_{s'} g_v[(s-s')&63] * Ys[r][s']
    {
        float accp[4][4];
        #pragma unroll
        for (int i = 0; i < 4; ++i)
            #pragma unroll
            for (int j = 0; j < 4; ++j) accp[i][j] = 0.f;
        for (int sp = 0; sp < 64; ++sp) {
            float yv[4], gvv[4];
            #pragma unroll
            for (int i = 0; i < 4; ++i) yv[i] = Ys[r0 + i][sp];
            #pragma unroll
            for (int j = 0; j < 4; ++j) gvv[j] = gsh[64 + ((s0 + j - sp) & 63)];
            #pragma unroll
            for (int i = 0; i < 4; ++i)
                #pragma unroll
                for (int j = 0; j < 4; ++j)
                    accp[i][j] = fmaf(yv[i], gvv[j], accp[i][j]);
        }
        #pragma unroll
        for (int i = 0; i < 4; ++i)
            #pragma unroll
            for (int j = 0; j < 4; ++j) Ts[r0 + i][s0 + j] = accp[i][j];
    }
    __syncthreads();

    // pass B (along H): out[r][s] = sum_{r'} g_u[(r-r')&63] * Ts[r'][s]
    {
        float accp[4][4];
        #pragma unroll
        for (int i = 0; i < 4; ++i)
            #pragma unroll
            for (int j = 0; j < 4; ++j) accp[i][j] = 0.f;
        for (int rp = 0; rp < 64; ++rp) {
            float tv[4], guv[4];
            #pragma unroll
            for (int j = 0; j < 4; ++j) tv[j] = Ts[rp][s0 + j];
            #pragma unroll
            for (int i = 0; i < 4; ++i) guv[i] = gsh[(r0 + i - rp) & 63];
            #pragma unroll
            for (int i = 0; i < 4; ++i)
                #pragma unroll
                for (int j = 0; j < 4; ++j)
                    accp[i][j] = fmaf(guv[i], tv[j], accp[i][j]);
        }
        #pragma unroll
        for (int i = 0; i < 4; ++i) {
            float4 o;
            o.x = accp[i][0]; o.y = accp[i][1]; o.z = accp[i][2]; o.w = accp[i][3];
            *reinterpret_cast<float4*>(yp + (r0 + i) * 64 + s0) = o;
        }
    }
}

extern "C" void kernel_launch(void* const* d_in, const int* in_sizes, int n_in,
                              void* d_out, int out_size, void* d_ws, size_t ws_size,
                              hipStream_t stream) {
    const float* x     = (const float*)d_in[0];
    const float* w     = (const float*)d_in[1];
    const float* alpha = (const float*)d_in[2];
    float* y = (float*)d_out;

    dim3 gridc(COUT / COB, 2, NB);   // co-block fastest => concurrent blocks share x tiles in L2
    conv3x3_kernel<<<gridc, 256, 0, stream>>>(x, w, y);
    arma_solve_kernel<<<dim3(NB * COUT), 256, 0, stream>>>(alpha, y);
}

// Round 2
// 516.744 us; speedup vs baseline: 19.4411x; 19.4411x over previous
//
#include <hip/hip_runtime.h>
#include <cmath>
#include <stdint.h>

#define HH 64
#define WD 64
#define CIN 256
#define COUT 256
#define NB 32
#define CK 32
#define NCHUNK 8

typedef _Float16 half8 __attribute__((ext_vector_type(8)));
typedef float floatx4 __attribute__((ext_vector_type(4)));

// ---------------------------------------------------------------------------
// Prep 1: w [co][ci][3][3] fp32  ->  wT fp16, layout
// [chunk 8][cb 4][tap 9][col 64][slot 4][j 8], slot = q ^ (co&3), ci = chunk*32+q*8+j
// so the conv kernel can stage a chunk's 36,864 B with verbatim b128 copies.
// ---------------------------------------------------------------------------
__global__ __launch_bounds__(256) void wprep_kernel(const float* __restrict__ w,
                                                    _Float16* __restrict__ wT) {
    const int idx = blockIdx.x * 256 + threadIdx.x;     // 589,824 total
    const int j    = idx & 7;
    const int s    = (idx >> 3) & 3;
    const int col  = (idx >> 5) & 63;
    const int tap  = (idx >> 11) % 9;
    const int rest = (idx >> 11) / 9;                   // chunk*4 + cb
    const int cb    = rest & 3;
    const int chunk = rest >> 2;
    const int co = cb * 64 + col;
    const int q  = s ^ (co & 3);
    const int ci = chunk * 32 + q * 8 + j;
    wT[idx] = (_Float16)w[(co * CIN + ci) * 9 + tap];
}

// ---------------------------------------------------------------------------
// Prep 2: per-channel circulant generators g_u, g_v -> gtab[c][isv][r] fp32
// ---------------------------------------------------------------------------
__global__ __launch_bounds__(256) void gprep_kernel(const float* __restrict__ alpha,
                                                    float* __restrict__ gtab) {
    const int gid = blockIdx.x * 256 + threadIdx.x;     // 32,768 = 256 ch * 2 * 64
    const int r   = gid & 63;
    const int isv = (gid >> 6) & 1;
    const int c   = gid >> 7;
    const float t0 = tanhf(alpha[c * 4 + isv * 2 + 0]);
    const float t1 = tanhf(alpha[c * 4 + isv * 2 + 1]);
    const float qq = 0.70710678118654752f;
    const float a0 = qq * (t0 + t1);   // tap -1
    const float a2 = qq * (t1 - t0);   // tap +1
    const float w0 = 0.09817477042468103f; // 2*pi/64
    float ssum = 0.f;
    for (int p = 0; p < 64; ++p) {
        const float th = w0 * (float)p;
        const float re = 1.f + (a0 + a2) * cosf(th);
        const float im = (a0 - a2) * sinf(th);
        const float inv = 1.f / (re * re + im * im);
        const float ph = w0 * (float)((p * r) & 63);
        ssum += (cosf(ph) * re + sinf(ph) * im) * inv;
    }
    gtab[gid] = ssum * (1.0f / 64.0f);
}

// ---------------------------------------------------------------------------
// Conv 3x3 as implicit GEMM, fp16 MFMA 16x16x32.
// Block: 256 thr = 4 waves. Tile: 256 pixels (4 rows x 64 cols) x 64 co.
// LDS x: [row 6][col 66][slot 4][8ci] fp16, XOR-swizzled; LDS w: [tap][col 64][slot 4][8].
// ---------------------------------------------------------------------------
__global__ __launch_bounds__(256, 2) void conv_mfma(const float* __restrict__ x,
                                                    const _Float16* __restrict__ wT,
                                                    float* __restrict__ y) {
    __shared__ __align__(16) _Float16 xs[6 * 66 * 32];   // 25,344 B
    __shared__ __align__(16) _Float16 wsl[9 * 64 * 32];  // 36,864 B
    const int tid  = threadIdx.x;
    const int lane = tid & 63;
    const int wv   = tid >> 6;
    const int m_l  = lane & 15;
    const int q_l  = lane >> 4;
    const int cb   = blockIdx.x;        // co-block (4)
    const int h0   = blockIdx.y * 4;    // row-block (16)
    const int n    = blockIdx.z;        // image (32)

    floatx4 acc[4][4];
    #pragma unroll
    for (int t = 0; t < 4; ++t)
        #pragma unroll
        for (int u = 0; u < 4; ++u) acc[t][u] = (floatx4)0.f;

    // zero the two halo columns (0 and 65), all slots — never overwritten
    if (tid < 48) {
        const int colz = (tid < 24) ? 0 : 65;
        const int uu = tid % 24;
        half8 z = (half8)(_Float16)0.f;
        *(half8*)&xs[((uu >> 2) * 66 + colz) * 32 + (uu & 3) * 8] = z;
    }

    const float* xg = x + (size_t)n * CIN * HH * WD;

    // hoisted per-kx fragment address pieces (XOR swizzle baked in)
    int swzA[3];
    #pragma unroll
    for (int kx = 0; kx < 3; ++kx)
        swzA[kx] = (m_l + kx) * 32 + (q_l ^ ((m_l + kx) & 3)) * 8;
    const int boffB = m_l * 32 + (q_l ^ (m_l & 3)) * 8;

    for (int chunk = 0; chunk < NCHUNK; ++chunk) {
        __syncthreads();
        // ---- stage w: verbatim 36,864 B copy (9 int4 per thread) ----
        const int4* wsrc = (const int4*)(wT + (size_t)(chunk * 4 + cb) * (9 * 64 * 32));
        int4* wdst = (int4*)wsl;
        #pragma unroll
        for (int i = 0; i < 9; ++i)
            wdst[tid + i * 256] = wsrc[tid + i * 256];
        // ---- stage x: wave wv stages ci-quad wv for rows 0..5 ----
        {
            const int ci0 = chunk * 32 + wv * 8;
            const int colx = 1 + lane;
            const int slot = (wv ^ (colx & 3)) * 8;
            #pragma unroll
            for (int k = 0; k < 6; ++k) {
                const int gh = h0 - 1 + k;
                half8 hv;
                if (gh >= 0 && gh < HH) {
                    #pragma unroll
                    for (int j = 0; j < 8; ++j)
                        hv[j] = (_Float16)xg[(size_t)(ci0 + j) * (HH * WD) + gh * WD + lane];
                } else {
                    hv = (half8)(_Float16)0.f;
                }
                *(half8*)&xs[(k * 66 + colx) * 32 + slot] = hv;
            }
        }
        __syncthreads();
        // ---- compute: 9 taps x 16 MFMAs ----
        #pragma unroll
        for (int ky = 0; ky < 3; ++ky) {
            const int rowbase = (wv + ky) * 66 * 32;
            #pragma unroll
            for (int kx = 0; kx < 3; ++kx) {
                const int tap = ky * 3 + kx;
                half8 bf[4], af[4];
                #pragma unroll
                for (int u = 0; u < 4; ++u)
                    bf[u] = *(const half8*)&wsl[tap * 2048 + u * 512 + boffB];
                #pragma unroll
                for (int t = 0; t < 4; ++t)
                    af[t] = *(const half8*)&xs[rowbase + t * 512 + swzA[kx]];
                #pragma unroll
                for (int t = 0; t < 4; ++t)
                    #pragma unroll
                    for (int u = 0; u < 4; ++u)
                        acc[t][u] = __builtin_amdgcn_mfma_f32_16x16x32_f16(bf[u], af[t], acc[t][u], 0, 0, 0);
            }
        }
    }

    // ---- epilogue: D rows = co (quad*4+reg), D cols = pixel (lane&15) ----
    const int row = h0 + wv;
    #pragma unroll
    for (int u = 0; u < 4; ++u) {
        #pragma unroll
        for (int r = 0; r < 4; ++r) {
            const int co = cb * 64 + u * 16 + q_l * 4 + r;
            float* yp = y + ((size_t)n * COUT + co) * (HH * WD) + row * WD;
            #pragma unroll
            for (int t = 0; t < 4; ++t)
                yp[t * 16 + m_l] = acc[t][u][r];
        }
    }
}

// ---------------------------------------------------------------------------
// Separable circulant deconvolution per (n,c) plane, in-place on y.
// ---------------------------------------------------------------------------
__global__ __launch_bounds__(256) void arma_solve_kernel(const float* __restrict__ gtab,
                                                         float* __restrict__ y) {
    __shared__ float Ys[64][66];
    __shared__ float Ts[64][66];
    __shared__ float gsh[128];
    const int tid = threadIdx.x;
    const int plane = blockIdx.x;       // n*256 + c
    const int c = plane & 255;
    float* yp = y + (size_t)plane * (64 * 64);

    #pragma unroll
    for (int k = 0; k < 4; ++k) {
        const int off = k * 1024 + tid * 4;
        const int rr = off >> 6;
        const int cc = off & 63;
        const float4 v = *reinterpret_cast<const float4*>(yp + off);
        Ys[rr][cc] = v.x; Ys[rr][cc + 1] = v.y; Ys[rr][cc + 2] = v.z; Ys[rr][cc + 3] = v.w;
    }
    if (tid < 128) gsh[tid] = gtab[(size_t)c * 128 + tid];
    __syncthreads();

    const int r0 = (tid >> 4) * 4;
    const int s0 = (tid & 15) * 4;

    // pass A (along W): Ts[r][s] = sum_{s'} g_v[(s-s')&63] * Ys[r][s']
    {
        float accp[4][4];
        #pragma unroll
        for (int i = 0; i < 4; ++i)
            #pragma unroll
            for (int j = 0; j < 4; ++j) accp[i][j] = 0.f;
        for (int sp = 0; sp < 64; ++sp) {
            float yv[4], gvv[4];
            #pragma unroll
            for (int i = 0; i < 4; ++i) yv[i] = Ys[r0 + i][sp];
            #pragma unroll
            for (int j = 0; j < 4; ++j) gvv[j] = gsh[64 + ((s0 + j - sp) & 63)];
            #pragma unroll
            for (int i = 0; i < 4; ++i)
                #pragma unroll
                for (int j = 0; j < 4; ++j)
                    accp[i][j] = fmaf(yv[i], gvv[j], accp[i][j]);
        }
        #pragma unroll
        for (int i = 0; i < 4; ++i)
            #pragma unroll
            for (int j = 0; j < 4; ++j) Ts[r0 + i][s0 + j] = accp[i][j];
    }
    __syncthreads();

    // pass B (along H): out[r][s] = sum_{r'} g_u[(r-r')&63] * Ts[r'][s]
    {
        float accp[4][4];
        #pragma unroll
        for (int i = 0; i < 4; ++i)
            #pragma unroll
            for (int j = 0; j < 4; ++j) accp[i][j] = 0.f;
        for (int rp = 0; rp < 64; ++rp) {
            float tv[4], guv[4];
            #pragma unroll
            for (int j = 0; j < 4; ++j) tv[j] = Ts[rp][s0 + j];
            #pragma unroll
            for (int i = 0; i < 4; ++i) guv[i] = gsh[(r0 + i - rp) & 63];
            #pragma unroll
            for (int i = 0; i < 4; ++i)
                #pragma unroll
                for (int j = 0; j < 4; ++j)
                    accp[i][j] = fmaf(guv[i], tv[j], accp[i][j]);
        }
        #pragma unroll
        for (int i = 0; i < 4; ++i) {
            float4 o;
            o.x = accp[i][0]; o.y = accp[i][1]; o.z = accp[i][2]; o.w = accp[i][3];
            *reinterpret_cast<float4*>(yp + (r0 + i) * 64 + s0) = o;
        }
    }
}

extern "C" void kernel_launch(void* const* d_in, const int* in_sizes, int n_in,
                              void* d_out, int out_size, void* d_ws, size_t ws_size,
                              hipStream_t stream) {
    const float* x     = (const float*)d_in[0];
    const float* w     = (const float*)d_in[1];
    const float* alpha = (const float*)d_in[2];
    float* y = (float*)d_out;

    _Float16* wT = (_Float16*)d_ws;                         // 1,179,648 B
    float* gtab  = (float*)((char*)d_ws + 1179648);         //   131,072 B

    wprep_kernel<<<dim3(2304), 256, 0, stream>>>(w, wT);
    gprep_kernel<<<dim3(128), 256, 0, stream>>>(alpha, gtab);
    conv_mfma<<<dim3(4, 16, NB), 256, 0, stream>>>(x, wT, y);
    arma_solve_kernel<<<dim3(NB * COUT), 256, 0, stream>>>(gtab, y);
}

// Round 3
// 497.874 us; speedup vs baseline: 20.1779x; 1.0379x over previous
//
#include <hip/hip_runtime.h>
#include <cmath>
#include <stdint.h>

#define HH 64
#define WD 64
#define CIN 256
#define COUT 256
#define NB 32

typedef _Float16 half8 __attribute__((ext_vector_type(8)));
typedef _Float16 half4 __attribute__((ext_vector_type(4)));
typedef float floatx4 __attribute__((ext_vector_type(4)));

// ---------------------------------------------------------------------------
// xprep: NCHW fp32 -> fp16 [n][chunk8][h64][w64][ci32]  (67 MB in ws)
// one block per (n, chunk, h): LDS transpose 32ci x 64w
// ---------------------------------------------------------------------------
__global__ __launch_bounds__(256) void xprep_kernel(const float* __restrict__ x,
                                                    _Float16* __restrict__ x16) {
    __shared__ _Float16 lt[32 * 72];
    const int tid = threadIdx.x;
    const int bid = blockIdx.x;           // n*512 + chunk*64 + h
    const int h = bid & 63;
    const int chunk = (bid >> 6) & 7;
    const int n = bid >> 9;
    {
        const int ci = tid >> 3;
        const int w8 = (tid & 7) * 8;
        const float* src = x + (((size_t)(n * 256 + chunk * 32 + ci) * 64 + h) * 64 + w8);
        const float4 a = *(const float4*)src;
        const float4 b = *(const float4*)(src + 4);
        half8 hv;
        hv[0] = (_Float16)a.x; hv[1] = (_Float16)a.y; hv[2] = (_Float16)a.z; hv[3] = (_Float16)a.w;
        hv[4] = (_Float16)b.x; hv[5] = (_Float16)b.y; hv[6] = (_Float16)b.z; hv[7] = (_Float16)b.w;
        *(half8*)&lt[ci * 72 + w8] = hv;
    }
    __syncthreads();
    {
        const int w = tid >> 2;
        const int kc = tid & 3;
        half8 hv;
        #pragma unroll
        for (int j = 0; j < 8; ++j) hv[j] = lt[(kc * 8 + j) * 72 + w];
        *(half8*)&x16[(((size_t)(n * 8 + chunk) * 64 + h) * 64 + w) * 32 + kc * 8] = hv;
    }
}

// ---------------------------------------------------------------------------
// wprep: w [co][ci][3][3] fp32 -> fp16 [chunk8][cb4][tap9][u4][q4][m16][j8]
// so a B-fragment is a single dwordx4 at (uniform base + lane*16B).
// ---------------------------------------------------------------------------
__global__ __launch_bounds__(256) void wprep_kernel(const float* __restrict__ w,
                                                    _Float16* __restrict__ w16) {
    const int idx = blockIdx.x * 256 + threadIdx.x;   // 589,824
    const int j = idx & 7;
    const int m = (idx >> 3) & 15;
    const int q = (idx >> 7) & 3;
    const int u = (idx >> 9) & 3;
    const int rest = idx >> 11;
    const int tap = rest % 9;
    const int rr = rest / 9;
    const int cb = rr & 3;
    const int chunk = rr >> 2;
    const int co = cb * 64 + u * 16 + m;
    const int ci = chunk * 32 + q * 8 + j;
    w16[idx] = (_Float16)w[(co * CIN + ci) * 9 + tap];
}

// ---------------------------------------------------------------------------
// gprep1: per-channel circulant generators -> gtab[c][isv][r] fp32
// ---------------------------------------------------------------------------
__global__ __launch_bounds__(256) void gprep1_kernel(const float* __restrict__ alpha,
                                                     float* __restrict__ gtab) {
    const int gid = blockIdx.x * 256 + threadIdx.x;     // 32,768
    const int r   = gid & 63;
    const int isv = (gid >> 6) & 1;
    const int c   = gid >> 7;
    const float t0 = tanhf(alpha[c * 4 + isv * 2 + 0]);
    const float t1 = tanhf(alpha[c * 4 + isv * 2 + 1]);
    const float qq = 0.70710678118654752f;
    const float a0 = qq * (t0 + t1);   // tap -1
    const float a2 = qq * (t1 - t0);   // tap +1
    const float w0 = 0.09817477042468103f; // 2*pi/64
    float ssum = 0.f;
    for (int p = 0; p < 64; ++p) {
        const float th = w0 * (float)p;
        const float re = 1.f + (a0 + a2) * cosf(th);
        const float im = (a0 - a2) * sinf(th);
        const float inv = 1.f / (re * re + im * im);
        const float ph = w0 * (float)((p * r) & 63);
        ssum += (cosf(ph) * re + sinf(ph) * im) * inv;
    }
    gtab[gid] = ssum * (1.0f / 64.0f);
}

// ---------------------------------------------------------------------------
// gprep2: expand to swizzled fp16 circulant matrices
// gm[c][which2][row64][kc8 ^ (row&7)][8],  G[row][col] = g[(row-col)&63]
// ---------------------------------------------------------------------------
__global__ __launch_bounds__(256) void gprep2_kernel(const float* __restrict__ gtab,
                                                     _Float16* __restrict__ gm) {
    const int idx = blockIdx.x * 256 + threadIdx.x;  // 262,144
    const int kc = idx & 7;
    const int row = (idx >> 3) & 63;
    const int which = (idx >> 9) & 1;
    const int c = idx >> 10;
    const float* g = gtab + c * 128 + which * 64;
    half8 hv;
    #pragma unroll
    for (int j = 0; j < 8; ++j)
        hv[j] = (_Float16)g[(row - (kc * 8 + j)) & 63];
    *(half8*)&gm[((size_t)(c * 2 + which) * 64 + row) * 64 + ((kc ^ (row & 7)) * 8)] = hv;
}

// ---------------------------------------------------------------------------
// Conv 3x3 as implicit GEMM, fp16 MFMA 16x16x32.
// Block: 4 waves; tile 64 co x 8 rows x 64 cols (128 px/wave, t=8, u=4).
// A (x) staged in LDS via b128 copies; B (w) loaded from global (L1/L2).
// ---------------------------------------------------------------------------
__global__ __launch_bounds__(256, 2) void conv_mfma(const _Float16* __restrict__ x16,
                                                    const _Float16* __restrict__ w16,
                                                    float* __restrict__ y) {
    __shared__ __align__(16) _Float16 xs[10 * 66 * 32];   // 42,240 B
    const int tid  = threadIdx.x;
    const int lane = tid & 63;
    const int wv   = tid >> 6;
    const int m    = lane & 15;
    const int q    = lane >> 4;
    const int cb   = blockIdx.x;        // 4
    const int h0   = blockIdx.y * 8;    // 8
    const int n    = blockIdx.z;        // 32

    floatx4 acc[8][4];
    #pragma unroll
    for (int t = 0; t < 8; ++t)
        #pragma unroll
        for (int u = 0; u < 4; ++u) acc[t][u] = (floatx4)0.f;

    int abase[3];
    #pragma unroll
    for (int kx = 0; kx < 3; ++kx)
        abase[kx] = ((wv * 2) * 66 + kx + m) * 32 + (q ^ ((m + kx) & 3)) * 8;

    for (int chunk = 0; chunk < 8; ++chunk) {
        __syncthreads();
        // ---- stage x tile: rows h0-1..h0+8, cols -1..64, 32 ci; b128 copies ----
        const _Float16* xc = x16 + (size_t)(n * 8 + chunk) * 131072;
        #pragma unroll
        for (int i = 0; i < 11; ++i) {
            const int idx = tid + i * 256;
            if (idx < 2640) {
                const int row = idx / 264;
                const int rem = idx - row * 264;
                const int cx  = rem >> 2;
                const int kc  = rem & 3;
                const int gh  = h0 - 1 + row;
                const int gw  = cx - 1;
                half8 v = (half8)(_Float16)0.f;
                if ((unsigned)gh < 64u && (unsigned)gw < 64u)
                    v = *(const half8*)&xc[((size_t)gh * 64 + gw) * 32 + kc * 8];
                *(half8*)&xs[(row * 66 + cx) * 32 + (kc ^ (cx & 3)) * 8] = v;
            }
        }
        __syncthreads();
        // ---- compute: 9 taps; B from global (L1/L2-resident) ----
        const _Float16* wchunk = w16 + (size_t)(chunk * 4 + cb) * 18432;
        #pragma unroll
        for (int ky = 0; ky < 3; ++ky) {
            #pragma unroll
            for (int kx = 0; kx < 3; ++kx) {
                const int tap = ky * 3 + kx;
                half8 bf[4];
                #pragma unroll
                for (int u = 0; u < 4; ++u)
                    bf[u] = *(const half8*)&wchunk[tap * 2048 + u * 512 + lane * 8];
                #pragma unroll
                for (int t = 0; t < 8; ++t) {
                    const half8 af = *(const half8*)&xs[abase[kx] + ((t >> 2) + ky) * 2112 + (t & 3) * 512];
                    #pragma unroll
                    for (int u = 0; u < 4; ++u)
                        acc[t][u] = __builtin_amdgcn_mfma_f32_16x16x32_f16(bf[u], af, acc[t][u], 0, 0, 0);
                }
            }
        }
    }

    // ---- epilogue: rows = co (q*4+r from operand1), cols = pixel (m) ----
    #pragma unroll
    for (int u = 0; u < 4; ++u) {
        #pragma unroll
        for (int r = 0; r < 4; ++r) {
            const int co = cb * 64 + u * 16 + q * 4 + r;
            float* yp = y + ((size_t)n * COUT + co) * (HH * WD);
            #pragma unroll
            for (int t = 0; t < 8; ++t)
                yp[(h0 + wv * 2 + (t >> 2)) * 64 + (t & 3) * 16 + m] = acc[t][u][r];
        }
    }
}

// ---------------------------------------------------------------------------
// Solve: per plane, Out = Gu * (Y * Gv^T) via two fp16 MFMA GEMMs, in-place.
// Wave wv owns row-tile [16wv,16wv+16). LDS round-trip transposes T.
// ---------------------------------------------------------------------------
__global__ __launch_bounds__(256, 4) void solve_mfma(const _Float16* __restrict__ gm,
                                                     float* __restrict__ y) {
    __shared__ __align__(16) _Float16 Ys[64 * 64];
    __shared__ __align__(16) _Float16 Tt[64 * 64];
    __shared__ __align__(16) _Float16 Gsh[2 * 64 * 64];
    const int tid  = threadIdx.x;
    const int lane = tid & 63;
    const int wv   = tid >> 6;
    const int m    = lane & 15;
    const int q    = lane >> 4;
    const int plane = blockIdx.x;       // n*256 + c
    const int c = plane & 255;
    float* yp = y + (size_t)plane * 4096;

    // stage Y (fp32 -> fp16, swizzled)
    {
        const int r = tid >> 2;
        const int c16 = (tid & 3) * 16;
        const float4 a = *(const float4*)&yp[r * 64 + c16];
        const float4 b = *(const float4*)&yp[r * 64 + c16 + 4];
        const float4 d = *(const float4*)&yp[r * 64 + c16 + 8];
        const float4 e = *(const float4*)&yp[r * 64 + c16 + 12];
        half8 h0v, h1v;
        h0v[0] = (_Float16)a.x; h0v[1] = (_Float16)a.y; h0v[2] = (_Float16)a.z; h0v[3] = (_Float16)a.w;
        h0v[4] = (_Float16)b.x; h0v[5] = (_Float16)b.y; h0v[6] = (_Float16)b.z; h0v[7] = (_Float16)b.w;
        h1v[0] = (_Float16)d.x; h1v[1] = (_Float16)d.y; h1v[2] = (_Float16)d.z; h1v[3] = (_Float16)d.w;
        h1v[4] = (_Float16)e.x; h1v[5] = (_Float16)e.y; h1v[6] = (_Float16)e.z; h1v[7] = (_Float16)e.w;
        const int kc0 = (tid & 3) * 2;
        *(half8*)&Ys[r * 64 + ((kc0 ^ (r & 7)) * 8)] = h0v;
        *(half8*)&Ys[r * 64 + (((kc0 + 1) ^ (r & 7)) * 8)] = h1v;
    }
    // stage G (already swizzled in ws)
    {
        const _Float16* gsrc = gm + (size_t)c * 8192;
        #pragma unroll
        for (int i = 0; i < 4; ++i) {
            const int idx = tid + i * 256;
            *(half8*)&Gsh[idx * 8] = *(const half8*)&gsrc[idx * 8];
        }
    }
    __syncthreads();

    // GEMM1: T = Y * Gv^T ; lane holds T[16wv+q*4+r][u*16+m] -> write Tt[s][r]
    {
        floatx4 acc1[4];
        #pragma unroll
        for (int u = 0; u < 4; ++u) acc1[u] = (floatx4)0.f;
        #pragma unroll
        for (int ks = 0; ks < 2; ++ks) {
            const int swz = ((ks * 4 + q) ^ (m & 7)) * 8;
            const half8 yf = *(const half8*)&Ys[(16 * wv + m) * 64 + swz];
            #pragma unroll
            for (int u = 0; u < 4; ++u) {
                const half8 gvf = *(const half8*)&Gsh[4096 + (u * 16 + m) * 64 + swz];
                acc1[u] = __builtin_amdgcn_mfma_f32_16x16x32_f16(yf, gvf, acc1[u], 0, 0, 0);
            }
        }
        #pragma unroll
        for (int u = 0; u < 4; ++u) {
            half4 hv;
            #pragma unroll
            for (int r = 0; r < 4; ++r) hv[r] = (_Float16)acc1[u][r];
            const int s = u * 16 + m;
            const int kc = 2 * wv + (q >> 1);
            *(half4*)&Tt[s * 64 + ((kc ^ (s & 7)) * 8) + (q & 1) * 4] = hv;
        }
    }
    __syncthreads();

    // GEMM2: Out = Gu * T ; store fp32 in-place
    {
        floatx4 acc2[4];
        #pragma unroll
        for (int u = 0; u < 4; ++u) acc2[u] = (floatx4)0.f;
        #pragma unroll
        for (int ks = 0; ks < 2; ++ks) {
            const int swz = ((ks * 4 + q) ^ (m & 7)) * 8;
            const half8 guf = *(const half8*)&Gsh[(16 * wv + m) * 64 + swz];
            #pragma unroll
            for (int u = 0; u < 4; ++u) {
                const half8 ttf = *(const half8*)&Tt[(u * 16 + m) * 64 + swz];
                acc2[u] = __builtin_amdgcn_mfma_f32_16x16x32_f16(guf, ttf, acc2[u], 0, 0, 0);
            }
        }
        #pragma unroll
        for (int u = 0; u < 4; ++u)
            #pragma unroll
            for (int r = 0; r < 4; ++r)
                yp[(16 * wv + q * 4 + r) * 64 + u * 16 + m] = acc2[u][r];
    }
}

extern "C" void kernel_launch(void* const* d_in, const int* in_sizes, int n_in,
                              void* d_out, int out_size, void* d_ws, size_t ws_size,
                              hipStream_t stream) {
    const float* x     = (const float*)d_in[0];
    const float* w     = (const float*)d_in[1];
    const float* alpha = (const float*)d_in[2];
    float* y = (float*)d_out;

    // workspace layout (bytes)
    _Float16* x16 = (_Float16*)d_ws;                               // 67,108,864 B
    _Float16* w16 = (_Float16*)((char*)d_ws + 67108864);           //  1,179,648 B
    _Float16* gm  = (_Float16*)((char*)d_ws + 68288512);           //  4,194,304 B
    float*    gtab = (float*)((char*)d_ws + 72482816);             //    131,072 B

    xprep_kernel <<<dim3(32 * 8 * 64), 256, 0, stream>>>(x, x16);
    wprep_kernel <<<dim3(2304),        256, 0, stream>>>(w, w16);
    gprep1_kernel<<<dim3(128),         256, 0, stream>>>(alpha, gtab);
    gprep2_kernel<<<dim3(1024),        256, 0, stream>>>(gtab, gm);
    conv_mfma    <<<dim3(4, 8, NB),    256, 0, stream>>>(x16, w16, y);
    solve_mfma   <<<dim3(NB * COUT),   256, 0, stream>>>(gm, y);
}